// Round 10
// baseline (38.404 us; speedup 1.0000x reference)
//
#include <hip/hip_runtime.h>

// Floyd-Steinberg halftoning, fused, 8-threads-per-tile (1 lane per column).
//
// Each 8x8 tile is owned by 8 consecutive lanes; lane owns original column
// `col`, all 3 channels. Per-lane state: 24 scalar load regs + p[8] gray +
// three 8-bit zero-masks -> ~50 live VGPRs, so ALL 24 loads issue in ONE
// up-front batch (single HBM latency exposure) with zero spill risk under
// __launch_bounds__(256,6). (R9 lesson: the 4-lane variant's merged batch
// needed ~100 regs under an 85-reg cap -> spill -> post-timing divergence.)
//
// FS (transposed orientation, matching reference swapaxes): FS row i = orig
// column i, owned by lane (lane&~7)|i; its 8 values arrive via
// __shfl(p[j], owner) with compile-time p index. FS runs redundantly in all
// 8 lanes (wave-free); each lane records only its own column's on-bits and
// stores its own column (3 planes). Every wave load/store instruction is a
// 256B-aligned dense 256B chunk.
//
// Grid: 8*131072 = 1048576 threads = 4096 blocks; VGPR~48 permits the full
// 8 waves/SIMD.
// Exact reference math, contract(off): ((0.114*s0)+(0.587*s1))+(0.299*s2).

#define IMG_H 1024
#define IMG_W 1024
#define NCH   3

__global__ __launch_bounds__(256, 6)
void fs_halftone_kernel(const float* __restrict__ in, float* __restrict__ out,
                        int n_imgs) {
#pragma clang fp contract(off)
    const int tiles_w = IMG_W / 8;                 // 128
    const int tiles_per_img = tiles_w * (IMG_H / 8);

    int gtid = blockIdx.x * blockDim.x + threadIdx.x;
    int tile = gtid >> 3;
    int col  = gtid & 7;                           // owned original column
    int lane = threadIdx.x & 63;
    int b  = tile / tiles_per_img;
    if (b >= n_imgs) return;
    int t  = tile % tiles_per_img;
    int th = t / tiles_w;
    int tw = t % tiles_w;

    const size_t imgstride = (size_t)IMG_H * IMG_W;
    const size_t col_off   = (size_t)(th * 8) * IMG_W + (size_t)(tw * 8) + (size_t)col;
    const float* base = in  + (size_t)b * NCH * imgstride + col_off;
    float*      obase = out + (size_t)b * NCH * imgstride + col_off;

    // ---- ONE up-front batch: 24 scalar loads (3 channels x 8 rows, own col)
    float a0[8], a1[8], a2[8];
#pragma unroll
    for (int r = 0; r < 8; ++r) a0[r] = base[0 * imgstride + (size_t)r * IMG_W];
#pragma unroll
    for (int r = 0; r < 8; ++r) a1[r] = base[1 * imgstride + (size_t)r * IMG_W];
#pragma unroll
    for (int r = 0; r < 8; ++r) a2[r] = base[2 * imgstride + (size_t)r * IMG_W];

    // ---- gray (exact reference tree) + per-channel zero-masks, own column --
    float p[8];                                    // gray, index = row r
    unsigned int zm0 = 0u, zm1 = 0u, zm2 = 0u;     // bit r
#pragma unroll
    for (int r = 0; r < 8; ++r) {
        float s0 = a0[r] * 255.0f;
        float s1 = a1[r] * 255.0f;
        float s2 = a2[r] * 255.0f;
        if (s0 == 0.0f) zm0 |= 1u << r;
        if (s1 == 0.0f) zm1 |= 1u << r;
        if (s2 == 0.0f) zm2 |= 1u << r;
        p[r] = ((0.114f * s0) + (0.587f * s1)) + (0.299f * s2);
    }

    // ---- Floyd-Steinberg on the TRANSPOSED tile (redundant across 8 lanes).
    // FS row i == original column i; FS col j == original row j.
    float nrow[8];
#pragma unroll
    for (int j = 0; j < 8; ++j) nrow[j] = 0.0f;

    unsigned int ob = 0u;                          // own column on-bits, bit j

#pragma unroll
    for (int i = 0; i < 8; ++i) {
        // broadcast column i from its owner lane (compile-time p index)
        float cv[8];
#pragma unroll
        for (int j = 0; j < 8; ++j)
            cv[j] = __shfl(p[j], (lane & ~7) | i);

        float errs[8];
        float er = 0.0f;
        unsigned int onb = 0u;
#pragma unroll
        for (int j = 0; j < 8; ++j) {
            float px  = cv[j] + nrow[j];
            float old = px + er;
            bool  on  = old > 127.0f;
            float nw  = on ? 255.0f : 0.0f;
            float e   = old - nw;
            er = e * 0.4375f;                      // 7/16
            errs[j] = e;
            if (on) onb |= 1u << j;
        }
        if (col == i) ob = onb;                    // keep own column's bits
#pragma unroll
        for (int j = 0; j < 8; ++j) {
            float en = (j < 7) ? errs[j + 1] : 0.0f;
            float ep = (j > 0) ? errs[j - 1] : 0.0f;
            nrow[j] = ((0.3125f * errs[j]) + (0.1875f * en)) + (0.0625f * ep);
        }
    }

    // ---- stores: own column, all 3 planes; out = (scaled==0) ? 0 : ht/255 --
#pragma unroll
    for (int ch = 0; ch < 3; ++ch) {
        unsigned int zm = (ch == 0) ? zm0 : ((ch == 1) ? zm1 : zm2);
#pragma unroll
        for (int r = 0; r < 8; ++r) {
            bool on = (ob >> r) & 1u;
            bool z  = (zm >> r) & 1u;
            obase[ch * imgstride + (size_t)r * IMG_W] = (on && !z) ? 1.0f : 0.0f;
        }
    }
}

extern "C" void kernel_launch(void* const* d_in, const int* in_sizes, int n_in,
                              void* d_out, int out_size, void* d_ws, size_t ws_size,
                              hipStream_t stream) {
    const float* in  = (const float*)d_in[0];
    float*       out = (float*)d_out;

    int n_imgs = in_sizes[0] / (NCH * IMG_H * IMG_W);  // 8
    int total_threads = 8 * n_imgs * (IMG_H / 8) * (IMG_W / 8);  // 8 per tile
    int block = 256;
    int grid = (total_threads + block - 1) / block;
    fs_halftone_kernel<<<grid, block, 0, stream>>>(in, out, n_imgs);
}